// Round 2
// baseline (100.621 us; speedup 1.0000x reference)
//
#include <hip/hip_runtime.h>

// TverskyProjection: out[r][p] = theta*inter - alpha*d_ab - beta*d_ba
//   a = x @ feature_bank  (2048 x 128), compared pairwise vs prototypes (512 x 128)
// Decomposition (u=relu(a), v=relu(p), su=[a>0], sv=[p>0]):
//   out = (theta+alpha+beta)*Sum(min(u,v)) - alpha*Sum(u*sv) - beta*Sum(v*su)

typedef __attribute__((ext_vector_type(8))) short s16x8;
typedef __attribute__((ext_vector_type(4))) float f32x4;

#define ROWS   2048   // B*S
#define IN_F   1024
#define NUM_F  128
#define OUT_F  512

__device__ __forceinline__ unsigned short f2bf(float f) {
    unsigned u = __builtin_bit_cast(unsigned, f);
    return (unsigned short)((u + 0x7FFFu + ((u >> 16) & 1u)) >> 16);
}

// ---------------- Kernel 1: A = x @ fb, write (relu(a), [a>0]) pairs ----------------
// Tile: 16 rows x 64 f-cols per block, K chunked by 128. 4 waves, each wave one
// 16x16 MFMA n-subtile. Grid = (2048/16) * (128/64) = 256 blocks.
__global__ __launch_bounds__(256) void k1_gemm_relu(const float* __restrict__ x,
                                                    const float* __restrict__ fb,
                                                    float2* __restrict__ up) {
    __shared__ unsigned short xs[16][136];   // 128 + 8 pad (bank spread, 16B align)
    __shared__ unsigned short fs[128][68];   // 64 + 4 pad (8B align, 2-way max)

    const int tid  = threadIdx.x;
    const int lane = tid & 63;
    const int w    = tid >> 6;
    const int bid  = blockIdx.x;
    const int fTile   = bid & 1;
    const int rowTile = bid >> 1;
    const int rowBase = rowTile * 16;
    const int n0      = fTile * 64;

    const int srow = tid >> 4;   // 0..15
    const int scol = tid & 15;   // 0..15

    f32x4 acc = {0.f, 0.f, 0.f, 0.f};

    for (int kc = 0; kc < 8; ++kc) {
        const int k0 = kc * 128;
        // stage x tile: 16 rows x 128 k, f32 -> bf16
        {
            const float* gx = x + (size_t)(rowBase + srow) * IN_F + k0 + scol * 8;
            float4 v0 = *(const float4*)gx;
            float4 v1 = *(const float4*)(gx + 4);
            s16x8 h;
            h[0] = (short)f2bf(v0.x); h[1] = (short)f2bf(v0.y);
            h[2] = (short)f2bf(v0.z); h[3] = (short)f2bf(v0.w);
            h[4] = (short)f2bf(v1.x); h[5] = (short)f2bf(v1.y);
            h[6] = (short)f2bf(v1.z); h[7] = (short)f2bf(v1.w);
            *(s16x8*)&xs[srow][scol * 8] = h;
        }
        // stage fb tile: 128 k x 64 n, f32 -> bf16
        #pragma unroll
        for (int jj = 0; jj < 8; ++jj) {
            const int kk = srow + 16 * jj;
            float4 v = *(const float4*)(fb + (size_t)(k0 + kk) * NUM_F + n0 + scol * 4);
            ushort4 h;
            h.x = f2bf(v.x); h.y = f2bf(v.y); h.z = f2bf(v.z); h.w = f2bf(v.w);
            *(ushort4*)&fs[kk][scol * 4] = h;
        }
        __syncthreads();

        #pragma unroll
        for (int ks = 0; ks < 4; ++ks) {
            const int kb = ks * 32 + (lane >> 4) * 8;
            s16x8 a = *(const s16x8*)&xs[lane & 15][kb];   // A[m][k], m=lane&15
            s16x8 b;
            const int nn = w * 16 + (lane & 15);           // B[k][n], n=lane&15
            #pragma unroll
            for (int i = 0; i < 8; ++i) b[i] = (short)fs[kb + i][nn];
            acc = __builtin_amdgcn_mfma_f32_16x16x32_bf16(a, b, acc, 0, 0, 0);
        }
        __syncthreads();
    }

    // C/D layout: col = lane&15, row = (lane>>4)*4 + reg   [learn_hip m89]
    const int col   = lane & 15;
    const int rbase = (lane >> 4) * 4;
    #pragma unroll
    for (int r = 0; r < 4; ++r) {
        const float c   = acc[r];
        const int   row = rowBase + rbase + r;
        const int   f   = n0 + w * 16 + col;
        up[(size_t)row * NUM_F + f] = make_float2(fmaxf(c, 0.f), c > 0.f ? 1.f : 0.f);
    }
}

// ---------------- Kernel 2: pairwise Tversky reduction ----------------
// 64 rows x 64 protos per block, 4x4 per thread (stride-16 mapping for bank
// spread), f chunked by 32. Grid = 32 * 8 = 256 blocks.
__global__ __launch_bounds__(256) void k2_tversky(const float2* __restrict__ up,
                                                  const float* __restrict__ prot,
                                                  const float* __restrict__ thp,
                                                  const float* __restrict__ alp,
                                                  const float* __restrict__ bep,
                                                  float* __restrict__ out) {
    __shared__ float2 us[64][34];   // 32 pairs + 2 pad (16B align, 272B stride)
    __shared__ float2 vs[64][34];

    const int tid = threadIdx.x;
    const int tc  = tid & 15;   // proto group
    const int tr  = tid >> 4;   // row group
    const int bid = blockIdx.x;
    const int colBase = (bid & 7) * 64;
    const int rowBase = (bid >> 3) * 64;

    float sm[4][4] = {{0.f}};
    float sa[4][4] = {{0.f}};
    float sp[4][4] = {{0.f}};

    for (int c = 0; c < 4; ++c) {
        const int f0 = c * 32;
        // stage u-pairs: 64 rows x 32 pairs (float4 = 2 pairs)
        #pragma unroll
        for (int t = 0; t < 4; ++t) {
            const int li  = tid + 256 * t;   // 0..1023
            const int row = li >> 4;
            const int p4  = li & 15;
            float4 v = *(const float4*)((const float*)up +
                        ((size_t)(rowBase + row) * NUM_F + f0) * 2 + p4 * 4);
            *(float4*)&us[row][p4 * 2] = v;
        }
        // stage v-pairs from raw prototypes: 64 protos x 32 f
        #pragma unroll
        for (int t = 0; t < 2; ++t) {
            const int li  = tid + 256 * t;   // 0..511
            const int row = li >> 3;
            const int q   = li & 7;
            float4 v = *(const float4*)(prot + (size_t)(colBase + row) * NUM_F + f0 + q * 4);
            float4 w0 = make_float4(fmaxf(v.x, 0.f), v.x > 0.f ? 1.f : 0.f,
                                    fmaxf(v.y, 0.f), v.y > 0.f ? 1.f : 0.f);
            float4 w1 = make_float4(fmaxf(v.z, 0.f), v.z > 0.f ? 1.f : 0.f,
                                    fmaxf(v.w, 0.f), v.w > 0.f ? 1.f : 0.f);
            *(float4*)&vs[row][q * 4]     = w0;
            *(float4*)&vs[row][q * 4 + 2] = w1;
        }
        __syncthreads();

        #pragma unroll 2
        for (int kk = 0; kk < 32; ++kk) {
            float2 uu[4], vv[4];
            #pragma unroll
            for (int i = 0; i < 4; ++i) uu[i] = us[tr + 16 * i][kk];
            #pragma unroll
            for (int j = 0; j < 4; ++j) vv[j] = vs[tc + 16 * j][kk];
            #pragma unroll
            for (int i = 0; i < 4; ++i) {
                #pragma unroll
                for (int j = 0; j < 4; ++j) {
                    sm[i][j] += fminf(uu[i].x, vv[j].x);   // min-intersection
                    sa[i][j] += uu[i].x * vv[j].y;         // u * [v>0]
                    sp[i][j] += vv[j].x * uu[i].y;         // v * [u>0]
                }
            }
        }
        __syncthreads();
    }

    const float th = *thp, al = *alp, be = *bep;
    const float c0 = th + al + be;
    #pragma unroll
    for (int i = 0; i < 4; ++i) {
        #pragma unroll
        for (int j = 0; j < 4; ++j) {
            out[(size_t)(rowBase + tr + 16 * i) * OUT_F + colBase + tc + 16 * j] =
                c0 * sm[i][j] - al * sa[i][j] - be * sp[i][j];
        }
    }
}

extern "C" void kernel_launch(void* const* d_in, const int* in_sizes, int n_in,
                              void* d_out, int out_size, void* d_ws, size_t ws_size,
                              hipStream_t stream) {
    const float* x    = (const float*)d_in[0];
    const float* fb   = (const float*)d_in[1];
    const float* prot = (const float*)d_in[2];
    const float* thp  = (const float*)d_in[3];
    const float* alp  = (const float*)d_in[4];
    const float* bep  = (const float*)d_in[5];
    float* out = (float*)d_out;
    float2* up = (float2*)d_ws;   // 2048 x 128 (u, su) pairs = 2 MB

    k1_gemm_relu<<<256, 256, 0, stream>>>(x, fb, up);
    k2_tversky<<<256, 256, 0, stream>>>(up, prot, thp, alp, bep, out);
}

// Round 3
// 92.452 us; speedup vs baseline: 1.0884x; 1.0884x over previous
//
#include <hip/hip_runtime.h>

// TverskyProjection: out[r][p] = theta*inter - alpha*d_ab - beta*d_ba
//   a = x @ feature_bank  (2048 x 128) vs prototypes (512 x 128)
// Decomposition (u=relu(a), v=relu(p), su=[a>0], sv=[p>0]):
//   out = (th+al+be)*Sm - al*Sa - be*Sp
//   Sm = sum_f min(u,v)   (VALU)
//   Sa = sum_f u*sv       (MFMA GEMM, bf16)
//   Sp = sum_f v*su       (MFMA GEMM, bf16)

typedef __attribute__((ext_vector_type(8))) short s16x8;
typedef __attribute__((ext_vector_type(4))) float f32x4;
typedef unsigned short u16;

#define ROWS   2048
#define IN_F   1024
#define NUM_F  128
#define OUT_F  512

__device__ __forceinline__ u16 f2bf(float f) {
    unsigned u = __builtin_bit_cast(unsigned, f);
    return (u16)((u + 0x7FFFu + ((u >> 16) & 1u)) >> 16);
}
__device__ __forceinline__ float bfu(u16 h) {
    return __builtin_bit_cast(float, (unsigned)h << 16);
}

// ws layout (u16 elements)
#define UBF_OFF   0                      // u bf16      [2048][128]
#define SUBF_OFF  (2048*128)             // su bf16     [2048][128]
#define VBF_OFF   (2*2048*128)           // v bf16      [512][128]
#define SVBF_OFF  (2*2048*128 + 512*128) // sv bf16     [512][128]
#define FBT_OFF   (2*2048*128 + 2*512*128) // fbT bf16  [128][1024]

// ---------------- k0: one-shot conversions ----------------
// blocks 0..31: fb [1024][128] f32 -> fbT [128][1024] bf16 (64x64 tiles, LDS transpose)
// blocks 32..39: prototypes -> (v=relu bf16, sv=indicator bf16)
__global__ __launch_bounds__(256) void k0_convert(const float* __restrict__ fb,
                                                  const float* __restrict__ prot,
                                                  u16* __restrict__ ws) {
    const int tid = threadIdx.x;
    const int b   = blockIdx.x;
    if (b < 32) {
        __shared__ u16 tr[64][72];   // tr[f_local][k_local]
        const int kt = b >> 1, ft = b & 1;
        #pragma unroll
        for (int t = 0; t < 4; ++t) {
            const int li = tid + 256 * t;          // 0..1023
            const int kl = li >> 4;                // 0..63
            const int f4 = li & 15;                // 0..15
            float4 v = *(const float4*)(fb + (size_t)(kt * 64 + kl) * NUM_F + ft * 64 + f4 * 4);
            tr[f4 * 4 + 0][kl] = f2bf(v.x);
            tr[f4 * 4 + 1][kl] = f2bf(v.y);
            tr[f4 * 4 + 2][kl] = f2bf(v.z);
            tr[f4 * 4 + 3][kl] = f2bf(v.w);
        }
        __syncthreads();
        u16* fbT = ws + FBT_OFF;
        const int fl = tid >> 2;                   // 0..63
        const int kq = tid & 3;                    // 0..3
        s16x8 a0 = *(const s16x8*)&tr[fl][kq * 16];
        s16x8 a1 = *(const s16x8*)&tr[fl][kq * 16 + 8];
        u16* dst = fbT + (size_t)(ft * 64 + fl) * IN_F + kt * 64 + kq * 16;
        *(s16x8*)dst       = a0;
        *(s16x8*)(dst + 8) = a1;
    } else {
        const int pb = b - 32;                     // 0..7
        u16* vbf  = ws + VBF_OFF;
        u16* svbf = ws + SVBF_OFF;
        #pragma unroll
        for (int t = 0; t < 8; ++t) {
            const int i4 = pb * 2048 + tid + 256 * t;   // float4 index, 16384 total
            float4 p = ((const float4*)prot)[i4];
            ushort4 vv, sv;
            vv.x = f2bf(fmaxf(p.x, 0.f)); sv.x = p.x > 0.f ? 0x3F80 : 0;
            vv.y = f2bf(fmaxf(p.y, 0.f)); sv.y = p.y > 0.f ? 0x3F80 : 0;
            vv.z = f2bf(fmaxf(p.z, 0.f)); sv.z = p.z > 0.f ? 0x3F80 : 0;
            vv.w = f2bf(fmaxf(p.w, 0.f)); sv.w = p.w > 0.f ? 0x3F80 : 0;
            ((ushort4*)vbf)[i4]  = vv;
            ((ushort4*)svbf)[i4] = sv;
        }
    }
}

// ---------------- k1: a = x @ fb via MFMA, write (u, su) bf16 ----------------
// 16 rows x 64 f per block; grid 256. B-frags contiguous from fbT.
__global__ __launch_bounds__(256) void k1_gemm_relu(const float* __restrict__ x,
                                                    u16* __restrict__ ws) {
    __shared__ u16 xs[16][136];
    __shared__ u16 fsT[64][136];
    const u16* fbT = ws + FBT_OFF;
    u16* ubf  = ws + UBF_OFF;
    u16* subf = ws + SUBF_OFF;

    const int tid  = threadIdx.x;
    const int lane = tid & 63;
    const int w    = tid >> 6;
    const int rowBase = (blockIdx.x >> 1) * 16;
    const int n0      = (blockIdx.x & 1) * 64;

    const int srow = tid >> 4;
    const int scol = tid & 15;

    f32x4 acc = {0.f, 0.f, 0.f, 0.f};

    for (int kc = 0; kc < 8; ++kc) {
        const int k0 = kc * 128;
        // x tile 16x128, f32->bf16
        {
            const float* gx = x + (size_t)(rowBase + srow) * IN_F + k0 + scol * 8;
            float4 v0 = *(const float4*)gx;
            float4 v1 = *(const float4*)(gx + 4);
            s16x8 h;
            h[0] = (short)f2bf(v0.x); h[1] = (short)f2bf(v0.y);
            h[2] = (short)f2bf(v0.z); h[3] = (short)f2bf(v0.w);
            h[4] = (short)f2bf(v1.x); h[5] = (short)f2bf(v1.y);
            h[6] = (short)f2bf(v1.z); h[7] = (short)f2bf(v1.w);
            *(s16x8*)&xs[srow][scol * 8] = h;
        }
        // fbT tile 64 f-rows x 128 k, straight bf16 copy
        #pragma unroll
        for (int t = 0; t < 4; ++t) {
            const int li  = tid + 256 * t;
            const int row = li >> 4;
            const int s8  = li & 15;
            *(s16x8*)&fsT[row][s8 * 8] =
                *(const s16x8*)(fbT + (size_t)(n0 + row) * IN_F + k0 + s8 * 8);
        }
        __syncthreads();

        #pragma unroll
        for (int ks = 0; ks < 4; ++ks) {
            const int kb = ks * 32 + (lane >> 4) * 8;
            s16x8 a = *(const s16x8*)&xs[lane & 15][kb];
            s16x8 b = *(const s16x8*)&fsT[w * 16 + (lane & 15)][kb];
            acc = __builtin_amdgcn_mfma_f32_16x16x32_bf16(a, b, acc, 0, 0, 0);
        }
        __syncthreads();
    }

    // C/D: col = lane&15, row = (lane>>4)*4 + r
    const int col   = lane & 15;
    const int rbase = (lane >> 4) * 4;
    #pragma unroll
    for (int r = 0; r < 4; ++r) {
        const float c   = acc[r];
        const int   row = rowBase + rbase + r;
        const int   f   = n0 + w * 16 + col;
        ubf [(size_t)row * NUM_F + f] = f2bf(fmaxf(c, 0.f));
        subf[(size_t)row * NUM_F + f] = c > 0.f ? 0x3F80 : 0;
    }
}

// ---------------- k2: Sm via VALU, Sa/Sp via MFMA, fused epilogue ----------------
// 32 rows x 64 protos per block; grid 512 (2 blocks/CU). Full f=128 staged.
__global__ __launch_bounds__(256) void k2_tversky(const u16* __restrict__ ws,
                                                  const float* __restrict__ thp,
                                                  const float* __restrict__ alp,
                                                  const float* __restrict__ bep,
                                                  float* __restrict__ out) {
    __shared__ u16 us[32][136];   // u bf16, 272B row stride (2-way max)
    __shared__ u16 ss[32][136];   // su
    __shared__ u16 vs[64][136];   // v
    __shared__ u16 ps[64][136];   // sv
    __shared__ float comb[32][68];

    const u16* ubf  = ws + UBF_OFF;
    const u16* subf = ws + SUBF_OFF;
    const u16* vbf  = ws + VBF_OFF;
    const u16* svbf = ws + SVBF_OFF;

    const int tid  = threadIdx.x;
    const int lane = tid & 63;
    const int w    = tid >> 6;
    const int tc   = tid & 15;
    const int tr   = (tid >> 4) & 15;
    const int rowBase = (blockIdx.x >> 3) * 32;
    const int colBase = (blockIdx.x & 7) * 64;

    // stage u/su (32x128) and v/sv (64x128)
    #pragma unroll
    for (int t = 0; t < 2; ++t) {
        const int li  = tid + 256 * t;   // 0..511
        const int row = li >> 4;
        const int s8  = li & 15;
        *(s16x8*)&us[row][s8 * 8] = *(const s16x8*)(ubf  + (size_t)(rowBase + row) * NUM_F + s8 * 8);
        *(s16x8*)&ss[row][s8 * 8] = *(const s16x8*)(subf + (size_t)(rowBase + row) * NUM_F + s8 * 8);
    }
    #pragma unroll
    for (int t = 0; t < 4; ++t) {
        const int li  = tid + 256 * t;   // 0..1023
        const int row = li >> 4;
        const int s8  = li & 15;
        *(s16x8*)&vs[row][s8 * 8] = *(const s16x8*)(vbf  + (size_t)(colBase + row) * NUM_F + s8 * 8);
        *(s16x8*)&ps[row][s8 * 8] = *(const s16x8*)(svbf + (size_t)(colBase + row) * NUM_F + s8 * 8);
    }
    __syncthreads();

    // ---- Sa/Sp via MFMA: wave w owns 16-row x 32-proto quadrant ----
    const int rowOff = (w >> 1) * 16;
    const int colOff = (w & 1) * 32;
    f32x4 asa[2] = {{0,0,0,0},{0,0,0,0}};
    f32x4 asp[2] = {{0,0,0,0},{0,0,0,0}};
    #pragma unroll
    for (int ks = 0; ks < 4; ++ks) {
        const int kb = ks * 32 + (lane >> 4) * 8;
        s16x8 au = *(const s16x8*)&us[rowOff + (lane & 15)][kb];
        s16x8 as = *(const s16x8*)&ss[rowOff + (lane & 15)][kb];
        #pragma unroll
        for (int nt = 0; nt < 2; ++nt) {
            s16x8 bv = *(const s16x8*)&vs[colOff + nt * 16 + (lane & 15)][kb];
            s16x8 bs = *(const s16x8*)&ps[colOff + nt * 16 + (lane & 15)][kb];
            asa[nt] = __builtin_amdgcn_mfma_f32_16x16x32_bf16(au, bs, asa[nt], 0, 0, 0);
            asp[nt] = __builtin_amdgcn_mfma_f32_16x16x32_bf16(as, bv, asp[nt], 0, 0, 0);
        }
    }

    // ---- Sm via VALU: thread-tile 2 rows x 4 protos ----
    float sm[2][4] = {{0.f}};
    #pragma unroll 4
    for (int g = 0; g < 16; ++g) {
        s16x8 U0 = *(const s16x8*)&us[tr][g * 8];
        s16x8 U1 = *(const s16x8*)&us[tr + 16][g * 8];
        s16x8 V0 = *(const s16x8*)&vs[tc][g * 8];
        s16x8 V1 = *(const s16x8*)&vs[tc + 16][g * 8];
        s16x8 V2 = *(const s16x8*)&vs[tc + 32][g * 8];
        s16x8 V3 = *(const s16x8*)&vs[tc + 48][g * 8];
        #pragma unroll
        for (int e = 0; e < 8; ++e) {
            const float u0 = bfu((u16)U0[e]);
            const float u1 = bfu((u16)U1[e]);
            const float v0 = bfu((u16)V0[e]);
            const float v1 = bfu((u16)V1[e]);
            const float v2 = bfu((u16)V2[e]);
            const float v3 = bfu((u16)V3[e]);
            sm[0][0] += fminf(u0, v0); sm[0][1] += fminf(u0, v1);
            sm[0][2] += fminf(u0, v2); sm[0][3] += fminf(u0, v3);
            sm[1][0] += fminf(u1, v0); sm[1][1] += fminf(u1, v1);
            sm[1][2] += fminf(u1, v2); sm[1][3] += fminf(u1, v3);
        }
    }

    const float th = *thp, al = *alp, be = *bep;
    const float c0 = th + al + be;

    // exchange MFMA-layout (al*Sa + be*Sp) through LDS
    __syncthreads();
    #pragma unroll
    for (int nt = 0; nt < 2; ++nt) {
        #pragma unroll
        for (int r = 0; r < 4; ++r) {
            const int row = rowOff + (lane >> 4) * 4 + r;
            const int cp  = colOff + nt * 16 + (lane & 15);
            comb[row][cp] = al * asa[nt][r] + be * asp[nt][r];
        }
    }
    __syncthreads();

    #pragma unroll
    for (int i = 0; i < 2; ++i) {
        #pragma unroll
        for (int j = 0; j < 4; ++j) {
            out[(size_t)(rowBase + tr + 16 * i) * OUT_F + colBase + tc + 16 * j] =
                c0 * sm[i][j] - comb[tr + 16 * i][tc + 16 * j];
        }
    }
}

extern "C" void kernel_launch(void* const* d_in, const int* in_sizes, int n_in,
                              void* d_out, int out_size, void* d_ws, size_t ws_size,
                              hipStream_t stream) {
    const float* x    = (const float*)d_in[0];
    const float* fb   = (const float*)d_in[1];
    const float* prot = (const float*)d_in[2];
    const float* thp  = (const float*)d_in[3];
    const float* alp  = (const float*)d_in[4];
    const float* bep  = (const float*)d_in[5];
    float* out = (float*)d_out;
    u16*   ws  = (u16*)d_ws;   // 1.5 MB used

    k0_convert  <<<40,  256, 0, stream>>>(fb, prot, ws);
    k1_gemm_relu<<<256, 256, 0, stream>>>(x, ws);
    k2_tversky  <<<512, 256, 0, stream>>>(ws, thp, alp, bep, out);
}

// Round 4
// 87.529 us; speedup vs baseline: 1.1496x; 1.0562x over previous
//
#include <hip/hip_runtime.h>

// TverskyProjection: out[r][p] = theta*inter - alpha*d_ab - beta*d_ba
//   a = x @ feature_bank (2048x128) vs prototypes (512x128)
// Decomposition (u=relu(a), v=relu(p), su=[u>0], sv=[v>0]):
//   out = (th+al+be)*Sm - al*Sa - be*Sp
//   Sm = sum_f min(u,v)   (VALU, packed f16 min/add)
//   Sa = sum_f u*sv       (MFMA f16, sv derived in-register)
//   Sp = sum_f v*su       (MFMA f16, su derived in-register)

typedef _Float16 f16;
typedef __attribute__((ext_vector_type(8))) _Float16 f16x8;
typedef __attribute__((ext_vector_type(4))) _Float16 f16x4;
typedef __attribute__((ext_vector_type(4))) float    f32x4;

#define ROWS   2048
#define IN_F   1024
#define NUM_F  128
#define OUT_F  512

// ws layout (f16 elements)
#define UH_OFF  0                 // u f16 [2048][128]
#define FBT_OFF (ROWS * NUM_F)    // fbT f16 [128][1024]

// ---------------- k0: fb [1024][128] f32 -> fbT [128][1024] f16 ----------------
// 32 blocks: 64k x 64f tile each, LDS transpose.
__global__ __launch_bounds__(256) void k0_fbT(const float* __restrict__ fb,
                                              f16* __restrict__ ws) {
    __shared__ f16 tr[64][72];   // row stride 144B (16B-aligned for b128 reads)
    const int tid = threadIdx.x;
    const int kt  = blockIdx.x >> 1;   // 0..15
    const int ft  = blockIdx.x & 1;    // 0..1
    #pragma unroll
    for (int t = 0; t < 4; ++t) {
        const int li = tid + 256 * t;      // 0..1023
        const int kl = li >> 4;            // 0..63
        const int f4 = li & 15;            // 0..15
        float4 v = *(const float4*)(fb + (size_t)(kt * 64 + kl) * NUM_F + ft * 64 + f4 * 4);
        tr[f4 * 4 + 0][kl] = (f16)v.x;
        tr[f4 * 4 + 1][kl] = (f16)v.y;
        tr[f4 * 4 + 2][kl] = (f16)v.z;
        tr[f4 * 4 + 3][kl] = (f16)v.w;
    }
    __syncthreads();
    f16* fbT = ws + FBT_OFF;
    const int fl = tid >> 2;   // 0..63
    const int kq = tid & 3;    // 0..3
    f16x8 a0 = *(const f16x8*)&tr[fl][kq * 16];
    f16x8 a1 = *(const f16x8*)&tr[fl][kq * 16 + 8];
    f16* dst = fbT + (size_t)(ft * 64 + fl) * IN_F + kt * 64 + kq * 16;
    *(f16x8*)dst       = a0;
    *(f16x8*)(dst + 8) = a1;
}

// ---------------- k1: a = x @ fb via MFMA f16, write u = relu(a) f16 ----------------
// 16 rows x 64 f per block; grid 256.
__global__ __launch_bounds__(256) void k1_gemm(const float* __restrict__ x,
                                               f16* __restrict__ ws) {
    __shared__ f16 xs[16][136];    // 272B stride
    __shared__ f16 fsT[64][136];
    const f16* fbT = ws + FBT_OFF;
    f16* UH = ws + UH_OFF;

    const int tid  = threadIdx.x;
    const int lane = tid & 63;
    const int w    = tid >> 6;
    const int rowBase = (blockIdx.x >> 1) * 16;
    const int n0      = (blockIdx.x & 1) * 64;
    const int srow = tid >> 4;
    const int scol = tid & 15;

    f32x4 acc = {0.f, 0.f, 0.f, 0.f};

    for (int kc = 0; kc < 8; ++kc) {
        const int k0 = kc * 128;
        // x tile 16x128, f32 -> f16
        {
            const float* gx = x + (size_t)(rowBase + srow) * IN_F + k0 + scol * 8;
            float4 v0 = *(const float4*)gx;
            float4 v1 = *(const float4*)(gx + 4);
            f16x8 h;
            h[0] = (f16)v0.x; h[1] = (f16)v0.y; h[2] = (f16)v0.z; h[3] = (f16)v0.w;
            h[4] = (f16)v1.x; h[5] = (f16)v1.y; h[6] = (f16)v1.z; h[7] = (f16)v1.w;
            *(f16x8*)&xs[srow][scol * 8] = h;
        }
        // fbT tile 64 f-rows x 128 k, straight f16 copy
        #pragma unroll
        for (int t = 0; t < 4; ++t) {
            const int li  = tid + 256 * t;
            const int row = li >> 4;
            const int s8  = li & 15;
            *(f16x8*)&fsT[row][s8 * 8] =
                *(const f16x8*)(fbT + (size_t)(n0 + row) * IN_F + k0 + s8 * 8);
        }
        __syncthreads();

        #pragma unroll
        for (int ks = 0; ks < 4; ++ks) {
            const int kb = ks * 32 + (lane >> 4) * 8;
            f16x8 a = *(const f16x8*)&xs[lane & 15][kb];
            f16x8 b = *(const f16x8*)&fsT[w * 16 + (lane & 15)][kb];
            acc = __builtin_amdgcn_mfma_f32_16x16x32_f16(a, b, acc, 0, 0, 0);
        }
        __syncthreads();
    }

    // C/D: col = lane&15, row = (lane>>4)*4 + r
    const int col   = lane & 15;
    const int rbase = (lane >> 4) * 4;
    #pragma unroll
    for (int r = 0; r < 4; ++r) {
        const float c   = acc[r];
        const int   row = rowBase + rbase + r;
        const int   f   = n0 + w * 16 + col;
        UH[(size_t)row * NUM_F + f] = (f16)fmaxf(c, 0.f);
    }
}

// ---------------- k2: Sm (pk f16) + Sa/Sp (MFMA, derived indicators) ----------------
// 64 rows x 64 protos per block; grid 256. Full f=128 staged. LDS 34.8KB.
__global__ __launch_bounds__(256) void k2_tversky(const f16* __restrict__ ws,
                                                  const float* __restrict__ prot,
                                                  const float* __restrict__ thp,
                                                  const float* __restrict__ alp,
                                                  const float* __restrict__ bep,
                                                  float* __restrict__ out) {
    __shared__ __align__(16) char smem[2 * 64 * 136 * 2];   // us | vs (34816 B)
    f16 (*us)[136] = (f16(*)[136])smem;                      // u rows, 272B stride
    f16 (*vs)[136] = (f16(*)[136])(smem + 64 * 136 * 2);     // v rows

    const f16* UH = ws + UH_OFF;

    const int tid  = threadIdx.x;
    const int lane = tid & 63;
    const int w    = tid >> 6;
    const int rowBase = (blockIdx.x >> 3) * 64;
    const int colBase = (blockIdx.x & 7) * 64;

    // stage u: 64 rows x 128 f16
    #pragma unroll
    for (int t = 0; t < 4; ++t) {
        const int li  = tid + 256 * t;   // 0..1023
        const int row = li >> 4;
        const int s8  = li & 15;
        *(f16x8*)&us[row][s8 * 8] = *(const f16x8*)(UH + (size_t)(rowBase + row) * NUM_F + s8 * 8);
    }
    // stage v = relu(prot) f16: 64 protos x 128 f (f32 source)
    #pragma unroll
    for (int t = 0; t < 8; ++t) {
        const int li  = tid + 256 * t;   // 0..2047
        const int row = li >> 5;
        const int q   = li & 31;
        float4 p = *(const float4*)(prot + (size_t)(colBase + row) * NUM_F + q * 4);
        f16x4 v;
        v[0] = (f16)fmaxf(p.x, 0.f); v[1] = (f16)fmaxf(p.y, 0.f);
        v[2] = (f16)fmaxf(p.z, 0.f); v[3] = (f16)fmaxf(p.w, 0.f);
        *(f16x4*)&vs[row][q * 4] = v;
    }
    __syncthreads();

    // ---- Sa/Sp via MFMA: wave w owns rows w*16..w*16+15, all 64 protos ----
    const int rowOff = w * 16;
    f32x4 asa[4], asp[4];
    #pragma unroll
    for (int nt = 0; nt < 4; ++nt) {
        asa[nt] = (f32x4){0.f, 0.f, 0.f, 0.f};
        asp[nt] = (f32x4){0.f, 0.f, 0.f, 0.f};
    }
    #pragma unroll
    for (int ks = 0; ks < 4; ++ks) {
        const int kb = ks * 32 + (lane >> 4) * 8;
        f16x8 au = *(const f16x8*)&us[rowOff + (lane & 15)][kb];
        f16x8 as_;
        #pragma unroll
        for (int e = 0; e < 8; ++e) as_[e] = au[e] > (f16)0 ? (f16)1 : (f16)0;
        #pragma unroll
        for (int nt = 0; nt < 4; ++nt) {
            f16x8 bv = *(const f16x8*)&vs[nt * 16 + (lane & 15)][kb];
            f16x8 bs;
            #pragma unroll
            for (int e = 0; e < 8; ++e) bs[e] = bv[e] > (f16)0 ? (f16)1 : (f16)0;
            asa[nt] = __builtin_amdgcn_mfma_f32_16x16x32_f16(au, bs, asa[nt], 0, 0, 0);
            asp[nt] = __builtin_amdgcn_mfma_f32_16x16x32_f16(as_, bv, asp[nt], 0, 0, 0);
        }
    }

    // ---- Sm via packed f16 min/add: thread tile 4 rows x 4 protos ----
    const int tr = tid >> 4;   // 0..15
    const int tc = tid & 15;   // 0..15
    f16x8 acc[4][4];
    #pragma unroll
    for (int i = 0; i < 4; ++i)
        #pragma unroll
        for (int j = 0; j < 4; ++j)
            acc[i][j] = (f16x8){0, 0, 0, 0, 0, 0, 0, 0};

    #pragma unroll
    for (int g = 0; g < 16; ++g) {
        f16x8 U[4], V[4];
        #pragma unroll
        for (int i = 0; i < 4; ++i) U[i] = *(const f16x8*)&us[tr + 16 * i][g * 8];
        #pragma unroll
        for (int j = 0; j < 4; ++j) V[j] = *(const f16x8*)&vs[tc + 16 * j][g * 8];
        #pragma unroll
        for (int i = 0; i < 4; ++i)
            #pragma unroll
            for (int j = 0; j < 4; ++j)
                acc[i][j] += __builtin_elementwise_min(U[i], V[j]);
    }

    const float th = *thp, al = *alp, be = *bep;
    const float c0 = th + al + be;

    // exchange al*Sa + be*Sp (MFMA layout) through LDS; comb overlays us
    __syncthreads();
    float (*comb)[68] = (float(*)[68])smem;   // 64x68 f32 = 17408B, 272B stride
    #pragma unroll
    for (int nt = 0; nt < 4; ++nt) {
        #pragma unroll
        for (int r = 0; r < 4; ++r) {
            const int row = rowOff + (lane >> 4) * 4 + r;
            const int cp  = nt * 16 + (lane & 15);
            comb[row][cp] = al * asa[nt][r] + be * asp[nt][r];
        }
    }
    __syncthreads();

    #pragma unroll
    for (int i = 0; i < 4; ++i) {
        #pragma unroll
        for (int j = 0; j < 4; ++j) {
            float s = 0.f;
            #pragma unroll
            for (int e = 0; e < 8; ++e) s += (float)acc[i][j][e];
            out[(size_t)(rowBase + tr + 16 * i) * OUT_F + colBase + tc + 16 * j] =
                c0 * s - comb[tr + 16 * i][tc + 16 * j];
        }
    }
}

extern "C" void kernel_launch(void* const* d_in, const int* in_sizes, int n_in,
                              void* d_out, int out_size, void* d_ws, size_t ws_size,
                              hipStream_t stream) {
    const float* x    = (const float*)d_in[0];
    const float* fb   = (const float*)d_in[1];
    const float* prot = (const float*)d_in[2];
    const float* thp  = (const float*)d_in[3];
    const float* alp  = (const float*)d_in[4];
    const float* bep  = (const float*)d_in[5];
    float* out = (float*)d_out;
    f16*   ws  = (f16*)d_ws;   // 0.75 MB used

    k0_fbT    <<<32,  256, 0, stream>>>(fb, ws);
    k1_gemm   <<<256, 256, 0, stream>>>(x, ws);
    k2_tversky<<<256, 256, 0, stream>>>(ws, prot, thp, alp, bep, out);
}